// Round 1
// baseline (151.489 us; speedup 1.0000x reference)
//
#include <hip/hip_runtime.h>
#include <hip/hip_bf16.h>

typedef __bf16 bf16x8 __attribute__((ext_vector_type(8)));
typedef __bf16 bf16x4 __attribute__((ext_vector_type(4)));
typedef float  floatx4 __attribute__((ext_vector_type(4)));

constexpr int Bc  = 2;
constexpr int Hc  = 16;
constexpr int Lc  = 2048;
constexpr int Dc  = 64;
constexpr int BHn = Bc * Hc;     // 32
constexpr int BM  = 64;          // query rows per block
constexpr int BN  = 64;          // keys per tile
constexpr int NQT = Lc / BM;     // 32 query tiles
constexpr int LDP = 72;          // padded LDS row stride (elems): 144 B, 16B-aligned rows, <=2-way conflicts

__global__ __launch_bounds__(256, 2)
void taylor_attn(const float* __restrict__ qp,
                 const float* __restrict__ kp,
                 const float* __restrict__ vp,
                 float* __restrict__ op)
{
    // QW: Q staging at start, then reused as the W (C-layout -> A-layout) round-trip buffer
    __shared__ __bf16 QW[BM * LDP];
    __shared__ __bf16 Ks[BN * LDP];   // K tile, row-major (key, d)
    __shared__ __bf16 VT[Dc * LDP];   // V tile transposed: (d, key)

    const int tid  = threadIdx.x;
    const int wv   = tid >> 6;        // wave 0..3 -> query rows [16*wv, 16*wv+16)
    const int lane = tid & 63;
    const int lm   = lane & 15;
    const int lq   = lane >> 4;

    const int qt = (NQT - 1) - (int)(blockIdx.x >> 5);   // heavy tiles first
    const int bh = (int)(blockIdx.x & (BHn - 1));

    const size_t base  = (size_t)bh * Lc * Dc;
    const float* qbase = qp + base + (size_t)qt * BM * Dc;
    const float* kbase = kp + base;
    const float* vbase = vp + base;
    float*       obase = op + base + (size_t)qt * BM * Dc;

    const int r0 = tid >> 4;   // 0..15 (staging row group)
    const int c4 = tid & 15;   // 0..15 (float4 column)

    // ---- stage Q (fp32 -> bf16) into QW ----
    #pragma unroll
    for (int rep = 0; rep < 4; ++rep) {
        const int row = r0 + rep * 16;
        floatx4 v = *(const floatx4*)(qbase + row * Dc + c4 * 4);
        bf16x4 b;
        b[0] = (__bf16)v[0]; b[1] = (__bf16)v[1];
        b[2] = (__bf16)v[2]; b[3] = (__bf16)v[3];
        *(bf16x4*)&QW[row * LDP + c4 * 4] = b;
    }
    __syncthreads();

    // Q A-frags for this wave's 16-row strip (held in registers for the whole kernel)
    bf16x8 qa[2];
    #pragma unroll
    for (int kf = 0; kf < 2; ++kf)
        qa[kf] = *(const bf16x8*)&QW[(16 * wv + lm) * LDP + kf * 32 + lq * 8];

    floatx4 oacc[4] = {};                       // O strip: 16 rows x 64 cols in C-layout
    float   zacc[4] = {0.f, 0.f, 0.f, 0.f};     // per-lane partial row sums

    for (int j = 0; j <= qt; ++j) {
        const float* kt = kbase + (size_t)j * BN * Dc;
        const float* vt = vbase + (size_t)j * BN * Dc;

        // ---- stage K (row-major) and V (transposed), fp32 -> bf16 ----
        #pragma unroll
        for (int rep = 0; rep < 4; ++rep) {
            const int row = r0 + rep * 16;
            floatx4 kv = *(const floatx4*)(kt + row * Dc + c4 * 4);
            bf16x4 kb;
            kb[0] = (__bf16)kv[0]; kb[1] = (__bf16)kv[1];
            kb[2] = (__bf16)kv[2]; kb[3] = (__bf16)kv[3];
            *(bf16x4*)&Ks[row * LDP + c4 * 4] = kb;

            floatx4 vv = *(const floatx4*)(vt + row * Dc + c4 * 4);
            VT[(c4 * 4 + 0) * LDP + row] = (__bf16)vv[0];
            VT[(c4 * 4 + 1) * LDP + row] = (__bf16)vv[1];
            VT[(c4 * 4 + 2) * LDP + row] = (__bf16)vv[2];
            VT[(c4 * 4 + 3) * LDP + row] = (__bf16)vv[3];
        }
        __syncthreads();

        // ---- S = Q * K^T  (M=16 strip, N=64, K=64) ----
        floatx4 sacc[4] = {};
        #pragma unroll
        for (int nb = 0; nb < 4; ++nb) {
            #pragma unroll
            for (int kf = 0; kf < 2; ++kf) {
                bf16x8 kb = *(const bf16x8*)&Ks[(nb * 16 + lm) * LDP + kf * 32 + lq * 8];
                sacc[nb] = __builtin_amdgcn_mfma_f32_16x16x32_bf16(qa[kf], kb, sacc[nb], 0, 0, 0);
            }
        }

        // ---- Taylor weight + causal mask + z accumulation; W -> LDS (A-layout friendly) ----
        const bool diag = (j == qt);
        #pragma unroll
        for (int nb = 0; nb < 4; ++nb) {
            #pragma unroll
            for (int r = 0; r < 4; ++r) {
                float s = sacc[nb][r] * 0.125f;         // scale = D^-0.5 folded in here
                float w = 1.0f + s + 0.5f * s * s;
                if (diag) {
                    const int qrow = 16 * wv + 4 * lq + r;   // query row within block
                    const int kcol = 16 * nb + lm;            // key col within tile
                    if (kcol > qrow) w = 0.0f;
                }
                zacc[r] += w;
                QW[(16 * wv + 4 * lq + r) * LDP + 16 * nb + lm] = (__bf16)w;
            }
        }
        __syncthreads();

        // ---- O += W * V  (A = W from LDS, B = V^T rows from LDS) ----
        bf16x8 wa[2];
        #pragma unroll
        for (int kf = 0; kf < 2; ++kf)
            wa[kf] = *(const bf16x8*)&QW[(16 * wv + lm) * LDP + kf * 32 + lq * 8];
        #pragma unroll
        for (int nb = 0; nb < 4; ++nb) {
            #pragma unroll
            for (int kf = 0; kf < 2; ++kf) {
                bf16x8 vb = *(const bf16x8*)&VT[(nb * 16 + lm) * LDP + kf * 32 + lq * 8];
                oacc[nb] = __builtin_amdgcn_mfma_f32_16x16x32_bf16(wa[kf], vb, oacc[nb], 0, 0, 0);
            }
        }
        __syncthreads();   // protect Ks/VT/QW before next iteration's staging
    }

    // ---- finalize: reduce z across the 16 lanes sharing each C-layout row, divide, store ----
    #pragma unroll
    for (int r = 0; r < 4; ++r) {
        float z = zacc[r];
        z += __shfl_xor(z, 1);
        z += __shfl_xor(z, 2);
        z += __shfl_xor(z, 4);
        z += __shfl_xor(z, 8);
        const float inv = 1.0f / (z + 1e-6f);
        const int row = 16 * wv + 4 * lq + r;
        #pragma unroll
        for (int nb = 0; nb < 4; ++nb)
            obase[row * Dc + 16 * nb + lm] = oacc[nb][r] * inv;
    }
}

extern "C" void kernel_launch(void* const* d_in, const int* in_sizes, int n_in,
                              void* d_out, int out_size, void* d_ws, size_t ws_size,
                              hipStream_t stream) {
    const float* q = (const float*)d_in[0];
    const float* k = (const float*)d_in[1];
    const float* v = (const float*)d_in[2];
    float* o = (float*)d_out;
    taylor_attn<<<dim3(NQT * BHn), dim3(256), 0, stream>>>(q, k, v, o);
}